// Round 1
// baseline (163.974 us; speedup 1.0000x reference)
//
#include <hip/hip_runtime.h>

#define BB 64
#define PP 25600
#define OO 32

struct PF { float x0,y0,x1,y1,a; };

__device__ __forceinline__ PF prior_pf(float4 pr){
    PF r;
    float hw = pr.z*0.5f, hh = pr.w*0.5f;
    r.x0 = pr.x - hw; r.y0 = pr.y - hh;
    r.x1 = pr.x + hw; r.y1 = pr.y + hh;
    r.a  = (r.x1 - r.x0) * (r.y1 - r.y0);
    return r;
}

__device__ __forceinline__ float iou_pf(float tx0,float ty0,float tx1,float ty1,float ta,const PF& p){
    float ltx = fmaxf(tx0, p.x0), lty = fmaxf(ty0, p.y0);
    float rbx = fminf(tx1, p.x1), rby = fminf(ty1, p.y1);
    float w = fmaxf(rbx - ltx, 0.f), h = fmaxf(rby - lty, 0.f);
    float inter = w * h;
    return inter / (ta + p.a - inter);
}

__device__ __forceinline__ float sl1f(float d){
    float ad = fabsf(d);
    return ad < 1.f ? 0.5f*ad*ad : ad - 0.5f;
}

__global__ void k_init(unsigned* __restrict__ w, int n){
    int i = blockIdx.x*256 + threadIdx.x;
    if (i < n) w[i] = 0u;
}

// grid (PP/1024, BB), 256 threads, 4 priors/thread.
// Per-prior best truth (argmax over t, first-index tie) -> best[] (fast path).
// Per-truth best prior (argmax over p, first-index tie) -> bp[] via u64 atomicMax.
template<bool STORE_BEST>
__global__ __launch_bounds__(256) void k_match(const float* __restrict__ priors,
        const float* __restrict__ targets,
        unsigned long long* __restrict__ bp,
        unsigned long long* __restrict__ best){
    const int b = blockIdx.y;
    const int pbase = blockIdx.x << 10;
    const int tid = threadIdx.x;
    __shared__ float s_tb[OO][4];
    __shared__ float s_ta[OO];
    if (tid < OO){
        const float* t = targets + ((size_t)b*OO + tid)*5;
        float x0=t[0], y0=t[1], x1=t[2], y1=t[3];
        s_tb[tid][0]=x0; s_tb[tid][1]=y0; s_tb[tid][2]=x1; s_tb[tid][3]=y1;
        s_ta[tid] = (x1-x0)*(y1-y0);
    }
    __syncthreads();
    PF pf[4]; int pidx[4];
    #pragma unroll
    for (int i=0;i<4;i++){
        pidx[i] = pbase + i*256 + tid;
        pf[i]   = prior_pf(((const float4*)priors)[pidx[i]]);
    }
    float bo[4] = {-1.f,-1.f,-1.f,-1.f};
    int   bi[4] = {0,0,0,0};
    const int lane = tid & 63;
    for (int t=0;t<OO;t++){
        float tx0=s_tb[t][0], ty0=s_tb[t][1], tx1=s_tb[t][2], ty1=s_tb[t][3], ta=s_ta[t];
        unsigned long long lkey = 0ull;
        #pragma unroll
        for (int i=0;i<4;i++){
            float v = iou_pf(tx0,ty0,tx1,ty1,ta,pf[i]);
            if (v > bo[i]){ bo[i]=v; bi[i]=t; }   // ascending t + strict > == first-index argmax
            unsigned long long key = ((unsigned long long)__float_as_uint(v) << 32)
                                   | (unsigned long long)(0xFFFFFFFFu - (unsigned)pidx[i]);
            if (key > lkey) lkey = key;           // ~p => smaller p wins ties (jnp.argmax)
        }
        #pragma unroll
        for (int d=32; d; d>>=1){
            unsigned long long o = __shfl_down(lkey, d);
            if (o > lkey) lkey = o;
        }
        if (lane == 0) atomicMax(&bp[b*OO + t], lkey);
    }
    if (STORE_BEST){
        #pragma unroll
        for (int i=0;i<4;i++)
            best[(size_t)b*PP + pidx[i]] =
                ((unsigned long long)__float_as_uint(bo[i]) << 32) | (unsigned)bi[i];
    }
}

// grid (PP/1024, BB), 1024 threads, 1 prior/thread.
// Forcing + conf + lse + rank value + smoothL1 for positives.
template<bool HAVE_BEST>
__global__ __launch_bounds__(1024) void k_loss(
        const float* __restrict__ loc, const float* __restrict__ conf,
        const float* __restrict__ priors, const float* __restrict__ targets,
        const unsigned long long* __restrict__ bp,
        const unsigned long long* __restrict__ best,
        float* __restrict__ vals,
        float* __restrict__ accf, float* __restrict__ csum_b, int* __restrict__ npos_b){
    const int b = blockIdx.y;
    const int p = (blockIdx.x << 10) + threadIdx.x;
    const int tid = threadIdx.x;
    __shared__ float s_tb[OO][4];
    __shared__ float s_ta[OO];
    __shared__ int s_lab[OO];
    __shared__ unsigned s_bpp[OO];
    __shared__ float s_lsum, s_csum;
    __shared__ int s_np;
    if (tid == 0){ s_lsum = 0.f; s_csum = 0.f; s_np = 0; }
    if (tid < OO){
        const float* t = targets + ((size_t)b*OO + tid)*5;
        s_tb[tid][0]=t[0]; s_tb[tid][1]=t[1]; s_tb[tid][2]=t[2]; s_tb[tid][3]=t[3];
        s_ta[tid] = (t[2]-t[0])*(t[3]-t[1]);
        s_lab[tid] = (int)t[4];
        s_bpp[tid] = 0xFFFFFFFFu - (unsigned)(bp[b*OO + tid] & 0xFFFFFFFFull);
    }
    __syncthreads();
    float4 pr = ((const float4*)priors)[p];
    float bo; int bi;
    if (HAVE_BEST){
        unsigned long long bk = best[(size_t)b*PP + p];
        bo = __uint_as_float((unsigned)(bk >> 32));
        bi = (int)(bk & 0xFFFFFFFFull);
    } else {
        PF pf = prior_pf(pr);
        bo = -1.f; bi = 0;
        #pragma unroll
        for (int t=0;t<OO;t++){
            float v = iou_pf(s_tb[t][0],s_tb[t][1],s_tb[t][2],s_tb[t][3],s_ta[t],pf);
            if (v > bo){ bo = v; bi = t; }
        }
    }
    // .at[best_prior_idx].set forcing; ascending t => last write wins (numpy scatter)
    #pragma unroll
    for (int t=0;t<OO;t++)
        if (s_bpp[t] == (unsigned)p){ bo = 2.0f; bi = t; }
    int c = (bo < 0.35f) ? 0 : (s_lab[bi] + 1);
    float2 cd = ((const float2*)conf)[(size_t)b*PP + p];
    float mx  = fmaxf(cd.x, cd.y);
    float lse = mx + log1pf(expf(fminf(cd.x, cd.y) - mx));
    int  cc  = c > 1 ? 1 : c;
    float g  = cc ? cd.y : cd.x;
    float lca = lse - g;           // > 0 always
    bool pos = c > 0;
    vals[(size_t)b*PP + p] = pos ? 0.f : lca;
    if (pos){
        float x0=s_tb[bi][0], y0=s_tb[bi][1], x1=s_tb[bi][2], y1=s_tb[bi][3];
        float gx = ((x0+x1)*0.5f - pr.x) / (0.1f*pr.z);
        float gy = ((y0+y1)*0.5f - pr.y) / (0.1f*pr.w);
        float gw = logf((x1-x0)/pr.z) / 0.2f;
        float gh = logf((y1-y0)/pr.w) / 0.2f;
        float4 ld = ((const float4*)loc)[(size_t)b*PP + p];
        float ll = sl1f(ld.x-gx)+sl1f(ld.y-gy)+sl1f(ld.z-gw)+sl1f(ld.w-gh);
        atomicAdd(&s_np, 1);
        atomicAdd(&s_csum, lca);
        atomicAdd(&s_lsum, ll);
    }
    __syncthreads();
    if (tid == 0 && s_np){
        atomicAdd(&accf[0], s_lsum);
        atomicAdd(&accf[2], (float)s_np);
        atomicAdd(&csum_b[b], s_csum);
        atomicAdd(&npos_b[b], s_np);
    }
}

// grid (BB), 1024 threads. Exact sum-of-top-k via bitwise radix select.
// All values >= 0 so float bits are order-isomorphic to uint bits.
__global__ __launch_bounds__(1024) void k_select(const float* __restrict__ vals,
        const float* __restrict__ csum_b, const int* __restrict__ npos_b,
        float* __restrict__ accf){
    const int b = blockIdx.x;
    const int tid = threadIdx.x;
    const unsigned* v = (const unsigned*)(vals + (size_t)b*PP);
    __shared__ unsigned s_cnt;
    __shared__ float s_sum;
    const int np = npos_b[b];
    int k = 3*np; if (k > PP-1) k = PP-1;
    float S = 0.f;
    float csum = csum_b[b];
    if (k > 0){
        unsigned cur = 0;                 // becomes bits of the k-th largest value
        for (int bit = 30; bit >= 0; --bit){
            unsigned test = cur | (1u << bit);
            if (tid == 0) s_cnt = 0;
            __syncthreads();
            unsigned c = 0;
            for (int p = tid; p < PP; p += 1024) c += (v[p] >= test) ? 1u : 0u;
            #pragma unroll
            for (int d=32; d; d>>=1) c += __shfl_down(c, d);
            if ((tid & 63) == 0 && c) atomicAdd(&s_cnt, c);
            __syncthreads();
            unsigned tot = s_cnt;
            __syncthreads();
            if (tot >= (unsigned)k) cur = test;
        }
        if (tid == 0){ s_cnt = 0; s_sum = 0.f; }
        __syncthreads();
        unsigned cg = 0; float sg = 0.f;
        for (int p = tid; p < PP; p += 1024){
            unsigned u = v[p];
            if (u > cur){ cg++; sg += __uint_as_float(u); }
        }
        #pragma unroll
        for (int d=32; d; d>>=1){ cg += __shfl_down(cg, d); sg += __shfl_down(sg, d); }
        if ((tid & 63) == 0 && cg){ atomicAdd(&s_cnt, cg); atomicAdd(&s_sum, sg); }
        __syncthreads();
        S = s_sum + (float)((unsigned)k - s_cnt) * __uint_as_float(cur);
    }
    if (tid == 0) atomicAdd(&accf[1], csum + S);
}

__global__ void k_fin(const float* __restrict__ accf, float* __restrict__ out){
    if (threadIdx.x == 0){
        float N = fmaxf(accf[2], 1.f);
        out[0] = accf[0] / N;
        out[1] = accf[1] / N;
    }
}

extern "C" void kernel_launch(void* const* d_in, const int* in_sizes, int n_in,
                              void* d_out, int out_size, void* d_ws, size_t ws_size,
                              hipStream_t stream){
    const float* loc     = (const float*)d_in[0];
    const float* conf    = (const float*)d_in[1];
    const float* priors  = (const float*)d_in[2];
    const float* targets = (const float*)d_in[3];
    float* out = (float*)d_out;
    char* ws = (char*)d_ws;

    unsigned long long* bp = (unsigned long long*)ws;            // 64*32*8 = 16384 B
    float* accf   = (float*)(ws + 16384);                        // [0]=lsum [1]=csum [2]=npos_tot
    float* csum_b = (float*)(ws + 16384 + 32);                   // 64 floats
    int*   npos_b = (int*)  (ws + 16384 + 32 + 256);             // 64 ints
    const size_t HDR = 17408;
    unsigned long long* best = (unsigned long long*)(ws + HDR);
    const size_t best_bytes = (size_t)BB*PP*8;
    const size_t need_fast = HDR + best_bytes + (size_t)BB*PP*4;

    k_init<<<17, 256, 0, stream>>>((unsigned*)ws, 16928/4);

    if (ws_size >= need_fast){
        float* vals = (float*)(ws + HDR + best_bytes);
        k_match<true><<<dim3(PP/1024, BB), 256, 0, stream>>>(priors, targets, bp, best);
        k_loss<true><<<dim3(PP/1024, BB), 1024, 0, stream>>>(loc, conf, priors, targets,
                                                             bp, best, vals, accf, csum_b, npos_b);
        k_select<<<BB, 1024, 0, stream>>>(vals, csum_b, npos_b, accf);
    } else {
        float* vals = (float*)(ws + HDR);
        k_match<false><<<dim3(PP/1024, BB), 256, 0, stream>>>(priors, targets, bp, nullptr);
        k_loss<false><<<dim3(PP/1024, BB), 1024, 0, stream>>>(loc, conf, priors, targets,
                                                              bp, nullptr, vals, accf, csum_b, npos_b);
        k_select<<<BB, 1024, 0, stream>>>(vals, csum_b, npos_b, accf);
    }
    k_fin<<<1, 64, 0, stream>>>(accf, out);
}

// Round 2
// 149.980 us; speedup vs baseline: 1.0933x; 1.0933x over previous
//
#include <hip/hip_runtime.h>

#define BB 64
#define PP 25600
#define OO 32
#define TH 0.35f

__device__ __forceinline__ float sl1f(float d){
    float ad = fabsf(d);
    return ad < 1.f ? 0.5f*ad*ad : ad - 0.5f;
}

// encode(truth, prior) + smooth-L1 against loc — matches reference rounding
__device__ __forceinline__ float locloss(float x0,float y0,float x1,float y1,
                                         float4 pr, float4 ld){
    float gx = ((x0+x1)*0.5f - pr.x) / (0.1f*pr.z);
    float gy = ((y0+y1)*0.5f - pr.y) / (0.1f*pr.w);
    float gw = logf((x1-x0)/pr.z) / 0.2f;
    float gh = logf((y1-y0)/pr.w) / 0.2f;
    return sl1f(ld.x-gx)+sl1f(ld.y-gy)+sl1f(ld.z-gw)+sl1f(ld.w-gh);
}

__global__ void k_init(unsigned* __restrict__ w, int n){
    int i = blockIdx.x*256 + threadIdx.x;
    if (i < n) w[i] = 0u;
}

// Fused match + loss. grid (PP/1024, BB), 256 threads, 4 priors/thread.
// Division-free argmax via cross-multiplication (u > 0 always).
__global__ __launch_bounds__(256) void k_main(
        const float* __restrict__ loc, const float* __restrict__ conf,
        const float* __restrict__ priors, const float* __restrict__ targets,
        unsigned long long* __restrict__ bp,
        float* __restrict__ vals,
        float* __restrict__ lsum_b, float* __restrict__ csum_b, int* __restrict__ npos_b){
    const int b = blockIdx.y;
    const int pbase = blockIdx.x << 10;
    const int tid = threadIdx.x;
    const int lane = tid & 63;
    __shared__ float4 s_tb[OO];
    __shared__ float  s_ta[OO];
    __shared__ int    s_lab[OO];
    if (tid < OO){
        const float* t = targets + ((size_t)b*OO + tid)*5;
        float x0=t[0],y0=t[1],x1=t[2],y1=t[3];
        s_tb[tid] = make_float4(x0,y0,x1,y1);
        s_ta[tid] = (x1-x0)*(y1-y0);
        s_lab[tid]= (int)t[4];
    }
    __syncthreads();

    float px0[4],py0[4],px1[4],py1[4],pa[4];
    float4 prv[4];
    int pidx[4];
    #pragma unroll
    for (int i=0;i<4;i++){
        pidx[i] = pbase + i*256 + tid;
        float4 pr = ((const float4*)priors)[pidx[i]];
        prv[i] = pr;
        float hw = pr.z*0.5f, hh = pr.w*0.5f;
        px0[i]=pr.x-hw; py0[i]=pr.y-hh; px1[i]=pr.x+hw; py1[i]=pr.y+hh;
        pa[i]=(px1[i]-px0[i])*(py1[i]-py0[i]);     // reference computes area from point_form coords
    }

    float binter[4], bu[4]; int bi[4];
    #pragma unroll
    for (int i=0;i<4;i++){ binter[i]=-1.f; bu[i]=1.f; bi[i]=0; }

    for (int t=0;t<OO;t++){
        float4 tb = s_tb[t];
        float ta = s_ta[t];
        float tin=-1.f, tu=1.f; int tp=0;
        #pragma unroll
        for (int i=0;i<4;i++){
            float ltx=fmaxf(tb.x,px0[i]), lty=fmaxf(tb.y,py0[i]);
            float rbx=fminf(tb.z,px1[i]), rby=fminf(tb.w,py1[i]);
            float w=fmaxf(rbx-ltx,0.f),  h=fmaxf(rby-lty,0.f);
            float inter=w*h;
            float u=ta+pa[i]-inter;
            // per-prior argmax over t: strict > + ascending t == first-index tie
            if (inter*bu[i] > binter[i]*u){ binter[i]=inter; bu[i]=u; bi[i]=t; }
            // per-truth argmax over p: strict > + ascending p == first-index tie
            if (inter*tu > tin*u){ tin=inter; tu=u; tp=pidx[i]; }
        }
        // wave butterfly argmax on (tin,tu,tp); tie -> smaller p
        #pragma unroll
        for (int d=1; d<64; d<<=1){
            float oin=__shfl_xor(tin,d), ou=__shfl_xor(tu,d);
            int   op =__shfl_xor(tp,d);
            float a = oin*tu, c2 = tin*ou;
            bool take = (a > c2) || (a == c2 && op < tp);
            if (take){ tin=oin; tu=ou; tp=op; }
        }
        if (lane==0){
            float iou = tin/tu;                      // tin>=0, tu>0
            unsigned long long key = ((unsigned long long)__float_as_uint(iou) << 32)
                                   | (unsigned long long)(0xFFFFFFFFu - (unsigned)tp);
            atomicMax(&bp[b*OO + t], key);
        }
    }

    // tail: unforced conf/lse/vals/loc-loss (forcing applied later by k_fix)
    float l_ls=0.f, l_cs=0.f; int l_np=0;
    #pragma unroll
    for (int i=0;i<4;i++){
        float iou = binter[i]/bu[i];
        int c = (iou < TH) ? 0 : (s_lab[bi[i]] + 1);
        float2 cd = ((const float2*)conf)[(size_t)b*PP + pidx[i]];
        float mx  = fmaxf(cd.x, cd.y);
        float lse = mx + log1pf(expf(fminf(cd.x,cd.y) - mx));
        float g   = (c >= 1) ? cd.y : cd.x;
        float lca = lse - g;
        bool pos = c > 0;
        vals[(size_t)b*PP + pidx[i]] = pos ? 0.f : lca;
        if (pos){
            float4 ld = ((const float4*)loc)[(size_t)b*PP + pidx[i]];
            float4 tb = s_tb[bi[i]];
            l_ls += locloss(tb.x,tb.y,tb.z,tb.w, prv[i], ld);
            l_cs += lca;
            l_np += 1;
        }
    }
    #pragma unroll
    for (int d=1; d<64; d<<=1){
        l_ls += __shfl_xor(l_ls,d);
        l_cs += __shfl_xor(l_cs,d);
        l_np += __shfl_xor(l_np,d);
    }
    if (lane==0){
        atomicAdd(&lsum_b[b], l_ls);
        atomicAdd(&csum_b[b], l_cs);
        atomicAdd(&npos_b[b], l_np);
    }
}

// Forcing fixup: <= 32 forced priors per batch; last-writer-wins scatter semantics.
__global__ __launch_bounds__(64) void k_fix(
        const float* __restrict__ loc, const float* __restrict__ conf,
        const float* __restrict__ priors, const float* __restrict__ targets,
        const unsigned long long* __restrict__ bp,
        float* __restrict__ vals,
        float* __restrict__ lsum_b, float* __restrict__ csum_b, int* __restrict__ npos_b){
    const int b = blockIdx.x;
    const int t = threadIdx.x;
    __shared__ float4 s_tb[OO];
    __shared__ float  s_ta[OO];
    __shared__ int    s_lab[OO];
    __shared__ unsigned s_p[OO];
    if (t < OO){
        const float* tt = targets + ((size_t)b*OO + t)*5;
        s_tb[t] = make_float4(tt[0],tt[1],tt[2],tt[3]);
        s_ta[t] = (tt[2]-tt[0])*(tt[3]-tt[1]);
        s_lab[t]= (int)tt[4];
        s_p[t]  = 0xFFFFFFFFu - (unsigned)(bp[b*OO + t] & 0xFFFFFFFFull);
    }
    __syncthreads();
    if (t >= OO) return;
    unsigned p = s_p[t];
    for (int t2=t+1; t2<OO; t2++) if (s_p[t2]==p) return;   // not last writer
    // recompute unforced state for prior p (identical comparison semantics as k_main)
    float4 pr = ((const float4*)priors)[p];
    float hw=pr.z*0.5f, hh=pr.w*0.5f;
    float px0=pr.x-hw, py0=pr.y-hh, px1=pr.x+hw, py1=pr.y+hh;
    float pa=(px1-px0)*(py1-py0);
    float binter=-1.f, buu=1.f; int bi=0;
    for (int k=0;k<OO;k++){
        float4 tb = s_tb[k];
        float ltx=fmaxf(tb.x,px0), lty=fmaxf(tb.y,py0);
        float rbx=fminf(tb.z,px1), rby=fminf(tb.w,py1);
        float w=fmaxf(rbx-ltx,0.f), h=fmaxf(rby-lty,0.f);
        float inter=w*h; float u=s_ta[k]+pa-inter;
        if (inter*buu > binter*u){ binter=inter; buu=u; bi=k; }
    }
    float iou = binter/buu;
    int  c0   = (iou < TH) ? 0 : (s_lab[bi] + 1);
    bool pos0 = c0 > 0;
    float2 cd = ((const float2*)conf)[(size_t)b*PP + p];
    float mx  = fmaxf(cd.x, cd.y);
    float lse = mx + log1pf(expf(fminf(cd.x,cd.y) - mx));
    float lca0 = lse - ((c0 >= 1) ? cd.y : cd.x);
    int   cn   = s_lab[t] + 1;
    float lcan = lse - ((cn >= 1) ? cd.y : cd.x);
    float4 ld = ((const float4*)loc)[(size_t)b*PP + p];
    float4 tbn = s_tb[t];
    float lln = locloss(tbn.x,tbn.y,tbn.z,tbn.w, pr, ld);
    float ll0 = 0.f;
    if (pos0){
        float4 tb0 = s_tb[bi];
        ll0 = locloss(tb0.x,tb0.y,tb0.z,tb0.w, pr, ld);
    }
    atomicAdd(&lsum_b[b], lln - ll0);
    atomicAdd(&csum_b[b], lcan - (pos0 ? lca0 : 0.f));
    if (!pos0) atomicAdd(&npos_b[b], 1);
    vals[(size_t)b*PP + p] = 0.f;
}

// Exact sum-of-top-k per batch: 31-bit radix select entirely from registers.
__global__ __launch_bounds__(1024) void k_select(const float* __restrict__ vals,
        const int* __restrict__ npos_b, float* __restrict__ sS){
    const int b = blockIdx.x;
    const int tid = threadIdx.x;
    const unsigned* g = (const unsigned*)(vals + (size_t)b*PP);
    unsigned uv[25];
    #pragma unroll
    for (int i=0;i<25;i++) uv[i] = g[tid + i*1024];
    __shared__ unsigned s_cnt[32];
    __shared__ float s_sum;
    if (tid < 32) s_cnt[tid] = 0;
    if (tid == 0) s_sum = 0.f;
    int np = npos_b[b];
    int k = 3*np; if (k > PP-1) k = PP-1;
    __syncthreads();
    float S = 0.f;
    if (k > 0){
        unsigned cur = 0;
        for (int bit=30; bit>=0; --bit){
            unsigned test = cur | (1u << bit);
            unsigned c = 0;
            #pragma unroll
            for (int i=0;i<25;i++) c += (uv[i] >= test) ? 1u : 0u;
            #pragma unroll
            for (int d=32; d; d>>=1) c += __shfl_down(c,d);
            if ((tid & 63)==0 && c) atomicAdd(&s_cnt[bit], c);
            __syncthreads();
            if (s_cnt[bit] >= (unsigned)k) cur = test;
        }
        unsigned cg=0; float sg=0.f;
        #pragma unroll
        for (int i=0;i<25;i++){
            unsigned u = uv[i];
            if (u > cur){ cg++; sg += __uint_as_float(u); }
        }
        #pragma unroll
        for (int d=32; d; d>>=1){ cg += __shfl_down(cg,d); sg += __shfl_down(sg,d); }
        if ((tid & 63)==0){ if (cg) atomicAdd(&s_cnt[31], cg); atomicAdd(&s_sum, sg); }
        __syncthreads();
        S = s_sum + (float)((unsigned)k - s_cnt[31]) * __uint_as_float(cur);
    }
    if (tid == 0) sS[b] = S;
}

__global__ void k_fin(const float* __restrict__ lsum_b, const float* __restrict__ csum_b,
                      const int* __restrict__ npos_b, const float* __restrict__ sS,
                      float* __restrict__ out){
    int t = threadIdx.x;           // 64 lanes == BB
    float ls = lsum_b[t];
    float cs = csum_b[t] + sS[t];
    int   np = npos_b[t];
    #pragma unroll
    for (int d=32; d; d>>=1){
        ls += __shfl_down(ls,d);
        cs += __shfl_down(cs,d);
        np += __shfl_down(np,d);
    }
    if (t==0){
        float N = fmaxf((float)np, 1.f);
        out[0] = ls / N;
        out[1] = cs / N;
    }
}

extern "C" void kernel_launch(void* const* d_in, const int* in_sizes, int n_in,
                              void* d_out, int out_size, void* d_ws, size_t ws_size,
                              hipStream_t stream){
    const float* loc     = (const float*)d_in[0];
    const float* conf    = (const float*)d_in[1];
    const float* priors  = (const float*)d_in[2];
    const float* targets = (const float*)d_in[3];
    float* out = (float*)d_out;
    char* ws = (char*)d_ws;

    unsigned long long* bp = (unsigned long long*)ws;       // 64*32*8 = 16384 B
    float* lsum_b = (float*)(ws + 16384);                   // 256 B
    float* csum_b = (float*)(ws + 16640);                   // 256 B
    int*   npos_b = (int*)  (ws + 16896);                   // 256 B
    float* sS     = (float*)(ws + 17152);                   // 256 B
    float* vals   = (float*)(ws + 17408);                   // 64*25600*4 = 6.55 MB

    k_init<<<17, 256, 0, stream>>>((unsigned*)ws, 17408/4);
    k_main<<<dim3(PP/1024, BB), 256, 0, stream>>>(loc, conf, priors, targets,
                                                  bp, vals, lsum_b, csum_b, npos_b);
    k_fix<<<BB, 64, 0, stream>>>(loc, conf, priors, targets, bp, vals,
                                 lsum_b, csum_b, npos_b);
    k_select<<<BB, 1024, 0, stream>>>(vals, npos_b, sS);
    k_fin<<<1, 64, 0, stream>>>(lsum_b, csum_b, npos_b, sS, out);
}

// Round 3
// 135.827 us; speedup vs baseline: 1.2072x; 1.1042x over previous
//
#include <hip/hip_runtime.h>

#define BB 64
#define PP 25600
#define OO 32
#define TH 0.35f
#define GX 10
#define SLICE (PP/GX)    // 2560 priors per block
#define NPL 10           // priors per lane (SLICE/256)

__device__ __forceinline__ float sl1f(float d){
    float ad = fabsf(d);
    return ad < 1.f ? 0.5f*ad*ad : ad - 0.5f;
}

__device__ __forceinline__ float locloss(float x0,float y0,float x1,float y1,
                                         float4 pr, float4 ld){
    float gx = ((x0+x1)*0.5f - pr.x) / (0.1f*pr.z);
    float gy = ((y0+y1)*0.5f - pr.y) / (0.1f*pr.w);
    float gw = logf((x1-x0)/pr.z) / 0.2f;
    float gh = logf((y1-y0)/pr.w) / 0.2f;
    return sl1f(ld.x-gx)+sl1f(ld.y-gy)+sl1f(ld.z-gw)+sl1f(ld.w-gh);
}

// wave-64 max of u64 key: ds_swizzle (xor 1..16, BitMode) + shfl for xor 32
__device__ __forceinline__ unsigned long long wmax64(unsigned long long k){
    #define WMAX_LVL(OFF) { \
        unsigned lo = (unsigned)__builtin_amdgcn_ds_swizzle((int)(unsigned)k, OFF); \
        unsigned hi = (unsigned)__builtin_amdgcn_ds_swizzle((int)(unsigned)(k>>32), OFF); \
        unsigned long long o = ((unsigned long long)hi<<32)|lo; if (o>k) k=o; }
    WMAX_LVL(0x041F)   // xor 1
    WMAX_LVL(0x081F)   // xor 2
    WMAX_LVL(0x101F)   // xor 4
    WMAX_LVL(0x201F)   // xor 8
    WMAX_LVL(0x401F)   // xor 16
    #undef WMAX_LVL
    { unsigned long long o = __shfl_xor(k, 32); if (o>k) k=o; }
    return k;
}

// Fused match + per-prior loss. grid (GX, BB), 256 threads, NPL priors/lane.
// t outer, priors inner: per-truth chain = 3 regs; one u64-key butterfly per t.
// Ordering compares use the exact-rational form inter1*s2 > inter2*s1
// (s = ta+pa); final iou = inter/(s-inter) reproduces reference f32 rounding.
__global__ __launch_bounds__(256) void k_main(
        const float* __restrict__ loc, const float* __restrict__ conf,
        const float* __restrict__ priors, const float* __restrict__ targets,
        unsigned long long* __restrict__ bp,
        float* __restrict__ vals,
        float* __restrict__ lsum_b, float* __restrict__ csum_b, int* __restrict__ npos_b){
    const int b   = blockIdx.y;
    const int tid = threadIdx.x;
    const int lane = tid & 63;
    const int p0  = blockIdx.x * SLICE + tid;

    __shared__ float4 s_tb[OO];
    __shared__ float  s_ta[OO];
    __shared__ int    s_lab[OO];
    if (tid < OO){
        const float* t = targets + ((size_t)b*OO + tid)*5;
        float x0=t[0],y0=t[1],x1=t[2],y1=t[3];
        s_tb[tid] = make_float4(x0,y0,x1,y1);
        s_ta[tid] = (x1-x0)*(y1-y0);
        s_lab[tid]= (int)t[4];
    }
    __syncthreads();

    float px0[NPL],py0[NPL],px1[NPL],py1[NPL],pa[NPL];
    #pragma unroll
    for (int j=0;j<NPL;j++){
        float4 pr = ((const float4*)priors)[p0 + j*256];
        float hw=pr.z*0.5f, hh=pr.w*0.5f;
        px0[j]=pr.x-hw; py0[j]=pr.y-hh; px1[j]=pr.x+hw; py1[j]=pr.y+hh;
        pa[j]=(px1[j]-px0[j])*(py1[j]-py0[j]);
    }
    float binter[NPL], bs[NPL]; int bi[NPL];
    #pragma unroll
    for (int j=0;j<NPL;j++){ binter[j]=-1.f; bs[j]=1.f; bi[j]=0; }

    #pragma unroll 2
    for (int t=0;t<OO;t++){
        float4 tb = s_tb[t];
        float ta = s_ta[t];
        float cin=-1.f, csn=1.f; unsigned cp=0;
        #pragma unroll
        for (int j=0;j<NPL;j++){
            float ltx=fmaxf(tb.x,px0[j]), lty=fmaxf(tb.y,py0[j]);
            float rbx=fminf(tb.z,px1[j]), rby=fminf(tb.w,py1[j]);
            float w=fmaxf(rbx-ltx,0.f), h=fmaxf(rby-lty,0.f);
            float inter=w*h;
            float s = ta + pa[j];
            // per-prior argmax over t (strict > + ascending t == first index)
            if (inter*bs[j] > binter[j]*s){ binter[j]=inter; bs[j]=s; bi[j]=t; }
            // per-truth argmax over p (strict > + ascending p == first index)
            if (inter*csn > cin*s){ cin=inter; csn=s; cp=(unsigned)(p0 + j*256); }
        }
        float iou = cin / (csn - cin);               // reference f32 rounding
        unsigned long long key = ((unsigned long long)__float_as_uint(iou)<<32)
                               | (unsigned long long)(0xFFFFFFFFu - cp);
        key = wmax64(key);                           // tie -> smaller p
        if (lane==0) atomicMax(&bp[b*OO+t], key);
    }

    // tail: unforced conf/lse/vals + positive accumulation (forcing in k_selfix)
    float l_ls=0.f, l_cs=0.f; int l_np=0;
    #pragma unroll
    for (int j=0;j<NPL;j++){
        int p = p0 + j*256;
        float biou = binter[j] / (bs[j] - binter[j]);
        int c = (biou < TH) ? 0 : (s_lab[bi[j]] + 1);
        float2 cd = ((const float2*)conf)[(size_t)b*PP + p];
        float mx = fmaxf(cd.x, cd.y);
        float lse = mx + log1pf(expf(fminf(cd.x,cd.y)-mx));
        float lca = lse - ((c>=1)? cd.y : cd.x);
        bool pos = c>0;
        vals[(size_t)b*PP + p] = pos ? 0.f : lca;
        if (pos){
            float4 pr = ((const float4*)priors)[p];
            float4 tb = s_tb[bi[j]];
            float4 ld = ((const float4*)loc)[(size_t)b*PP + p];
            l_ls += locloss(tb.x,tb.y,tb.z,tb.w, pr, ld);
            l_cs += lca; l_np++;
        }
    }
    #pragma unroll
    for (int d=1; d<64; d<<=1){
        l_ls += __shfl_xor(l_ls,d);
        l_cs += __shfl_xor(l_cs,d);
        l_np += __shfl_xor(l_np,d);
    }
    if (lane==0){
        atomicAdd(&lsum_b[b], l_ls);
        atomicAdd(&csum_b[b], l_cs);
        atomicAdd(&npos_b[b], l_np);
    }
}

// Phase A: forcing fixup (<=32 priors, last-writer-wins). Phase B: exact
// sum-of-top-k via 31-round bitwise radix select from registers.
__global__ __launch_bounds__(1024) void k_selfix(
        const float* __restrict__ loc, const float* __restrict__ conf,
        const float* __restrict__ priors, const float* __restrict__ targets,
        const unsigned long long* __restrict__ bp,
        float* __restrict__ vals,
        float* __restrict__ lsum_b, float* __restrict__ csum_b, int* __restrict__ npos_b,
        float* __restrict__ sS){
    const int b = blockIdx.x;
    const int tid = threadIdx.x;
    __shared__ float4 s_tb[OO];
    __shared__ float  s_ta[OO];
    __shared__ int    s_lab[OO];
    __shared__ unsigned s_p[OO];
    __shared__ unsigned s_cnt[32];
    __shared__ float s_sum;
    __shared__ int s_k;
    if (tid < OO){
        const float* tt = targets + ((size_t)b*OO + tid)*5;
        s_tb[tid] = make_float4(tt[0],tt[1],tt[2],tt[3]);
        s_ta[tid] = (tt[2]-tt[0])*(tt[3]-tt[1]);
        s_lab[tid]= (int)tt[4];
        s_p[tid]  = 0xFFFFFFFFu - (unsigned)(bp[b*OO + tid] & 0xFFFFFFFFull);
        s_cnt[tid] = 0;
    }
    if (tid == 0) s_sum = 0.f;
    __syncthreads();
    if (tid < OO){
        unsigned p = s_p[tid];
        bool last = true;
        for (int t2=tid+1; t2<OO; t2++) if (s_p[t2]==p) last = false;
        if (last){
            // recompute unforced state for prior p — identical compare semantics
            float4 pr = ((const float4*)priors)[p];
            float hw=pr.z*0.5f, hh=pr.w*0.5f;
            float qx0=pr.x-hw, qy0=pr.y-hh, qx1=pr.x+hw, qy1=pr.y+hh;
            float qa=(qx1-qx0)*(qy1-qy0);
            float binter=-1.f, bss=1.f; int bi=0;
            for (int k2=0;k2<OO;k2++){
                float4 tb = s_tb[k2];
                float ltx=fmaxf(tb.x,qx0), lty=fmaxf(tb.y,qy0);
                float rbx=fminf(tb.z,qx1), rby=fminf(tb.w,qy1);
                float w=fmaxf(rbx-ltx,0.f), h=fmaxf(rby-lty,0.f);
                float inter=w*h; float s=s_ta[k2]+qa;
                if (inter*bss > binter*s){ binter=inter; bss=s; bi=k2; }
            }
            float biou = binter/(bss-binter);
            int  c0   = (biou < TH) ? 0 : (s_lab[bi] + 1);
            bool pos0 = c0 > 0;
            float2 cd = ((const float2*)conf)[(size_t)b*PP + p];
            float mx  = fmaxf(cd.x, cd.y);
            float lse = mx + log1pf(expf(fminf(cd.x,cd.y)-mx));
            float lca0 = lse - ((c0 >= 1) ? cd.y : cd.x);
            int   cn   = s_lab[tid] + 1;
            float lcan = lse - ((cn >= 1) ? cd.y : cd.x);
            float4 ld  = ((const float4*)loc)[(size_t)b*PP + p];
            float4 tbn = s_tb[tid];
            float lln = locloss(tbn.x,tbn.y,tbn.z,tbn.w, pr, ld);
            float ll0 = 0.f;
            if (pos0){
                float4 tb0 = s_tb[bi];
                ll0 = locloss(tb0.x,tb0.y,tb0.z,tb0.w, pr, ld);
            }
            atomicAdd(&lsum_b[b], lln - ll0);
            atomicAdd(&csum_b[b], lcan - (pos0 ? lca0 : 0.f));
            if (!pos0) atomicAdd(&npos_b[b], 1);
            vals[(size_t)b*PP + p] = 0.f;
        }
    }
    __syncthreads();
    if (tid == 0){
        int np = atomicAdd(&npos_b[b], 0);     // L2 read-through
        int k = 3*np; if (k > PP-1) k = PP-1;
        s_k = k;
    }
    __syncthreads();
    const unsigned* g = (const unsigned*)(vals + (size_t)b*PP);
    unsigned uv[25];
    #pragma unroll
    for (int i=0;i<25;i++) uv[i] = g[tid + (i<<10)];
    const int k = s_k;
    float S = 0.f;
    if (k > 0){
        unsigned cur = 0;
        for (int bit=30; bit>=0; --bit){
            unsigned test = cur | (1u << bit);
            unsigned c = 0;
            #pragma unroll
            for (int i=0;i<25;i++) c += (uv[i] >= test) ? 1u : 0u;
            #pragma unroll
            for (int d=32; d; d>>=1) c += __shfl_down(c,d);
            if ((tid & 63)==0 && c) atomicAdd(&s_cnt[bit], c);
            __syncthreads();
            if (s_cnt[bit] >= (unsigned)k) cur = test;
        }
        unsigned cg=0; float sg=0.f;
        #pragma unroll
        for (int i=0;i<25;i++){
            unsigned u = uv[i];
            if (u > cur){ cg++; sg += __uint_as_float(u); }
        }
        #pragma unroll
        for (int d=32; d; d>>=1){ cg += __shfl_down(cg,d); sg += __shfl_down(sg,d); }
        if ((tid & 63)==0){ if (cg) atomicAdd(&s_cnt[31], cg); atomicAdd(&s_sum, sg); }
        __syncthreads();
        S = s_sum + (float)((unsigned)k - s_cnt[31]) * __uint_as_float(cur);
    }
    if (tid == 0) sS[b] = S;
}

__global__ void k_fin(const float* __restrict__ lsum_b, const float* __restrict__ csum_b,
                      const int* __restrict__ npos_b, const float* __restrict__ sS,
                      float* __restrict__ out){
    int t = threadIdx.x;           // 64 lanes == BB
    float ls = lsum_b[t];
    float cs = csum_b[t] + sS[t];
    int   np = npos_b[t];
    #pragma unroll
    for (int d=32; d; d>>=1){
        ls += __shfl_down(ls,d);
        cs += __shfl_down(cs,d);
        np += __shfl_down(np,d);
    }
    if (t==0){
        float N = fmaxf((float)np, 1.f);
        out[0] = ls / N;
        out[1] = cs / N;
    }
}

extern "C" void kernel_launch(void* const* d_in, const int* in_sizes, int n_in,
                              void* d_out, int out_size, void* d_ws, size_t ws_size,
                              hipStream_t stream){
    const float* loc     = (const float*)d_in[0];
    const float* conf    = (const float*)d_in[1];
    const float* priors  = (const float*)d_in[2];
    const float* targets = (const float*)d_in[3];
    float* out = (float*)d_out;
    char* ws = (char*)d_ws;

    unsigned long long* bp = (unsigned long long*)ws;       // [0,16384)
    float* lsum_b = (float*)(ws + 16384);                   // [16384,16640)
    float* csum_b = (float*)(ws + 16640);                   // [16640,16896)
    int*   npos_b = (int*)  (ws + 16896);                   // [16896,17152)
    float* sS     = (float*)(ws + 17152);                   // [17152,17408)
    float* vals   = (float*)(ws + 17408);                   // 6.55 MB

    hipMemsetAsync(ws, 0, 17408, stream);
    k_main<<<dim3(GX, BB), 256, 0, stream>>>(loc, conf, priors, targets,
                                             bp, vals, lsum_b, csum_b, npos_b);
    k_selfix<<<BB, 1024, 0, stream>>>(loc, conf, priors, targets, bp, vals,
                                      lsum_b, csum_b, npos_b, sS);
    k_fin<<<1, 64, 0, stream>>>(lsum_b, csum_b, npos_b, sS, out);
}

// Round 4
// 104.901 us; speedup vs baseline: 1.5631x; 1.2948x over previous
//
#include <hip/hip_runtime.h>

#define BB 64
#define PP 25600
#define OO 32
#define TH 0.35f
#define GX 25
#define SLICE 1024       // priors per block
#define NPL 4            // priors per lane
#define TC 8             // truths per chunk

__device__ __forceinline__ float sl1f(float d){
    float ad = fabsf(d);
    return ad < 1.f ? 0.5f*ad*ad : ad - 0.5f;
}

__device__ __forceinline__ float locloss(float x0,float y0,float x1,float y1,
                                         float4 pr, float4 ld){
    float gx = ((x0+x1)*0.5f - pr.x) / (0.1f*pr.z);
    float gy = ((y0+y1)*0.5f - pr.y) / (0.1f*pr.w);
    float gw = logf((x1-x0)/pr.z) / 0.2f;
    float gh = logf((y1-y0)/pr.w) / 0.2f;
    return sl1f(ld.x-gx)+sl1f(ld.y-gy)+sl1f(ld.z-gw)+sl1f(ld.w-gh);
}

// u64 max across a 32-lane half-wave (ds_swizzle BitMode, and=0x1F => groups of 32)
__device__ __forceinline__ unsigned long long hmax32(unsigned long long k){
    #define HLVL(OFF) { \
        unsigned lo = (unsigned)__builtin_amdgcn_ds_swizzle((int)(unsigned)k, OFF); \
        unsigned hi = (unsigned)__builtin_amdgcn_ds_swizzle((int)(unsigned)(k>>32), OFF); \
        unsigned long long o = ((unsigned long long)hi<<32)|lo; if (o>k) k=o; }
    HLVL(0x041F) HLVL(0x081F) HLVL(0x101F) HLVL(0x201F) HLVL(0x401F)
    #undef HLVL
    return k;
}

// Fused match + per-prior loss. grid (GX, BB), 256 threads, NPL priors/lane.
// Per-truth argmax: per-lane best -> IEEE-rounded iou key -> chunked LDS
// reduction by 32-thread row groups (no per-t butterfly).
__global__ __launch_bounds__(256) void k_main(
        const float* __restrict__ loc, const float* __restrict__ conf,
        const float* __restrict__ priors, const float* __restrict__ targets,
        unsigned long long* __restrict__ bp,
        float* __restrict__ vals,
        float* __restrict__ lsum_b, float* __restrict__ csum_b, int* __restrict__ npos_b){
    const int b   = blockIdx.y;
    const int tid = threadIdx.x;
    const int lane = tid & 63;
    const int p0  = blockIdx.x * SLICE + tid;

    __shared__ float4 s_tb[OO];
    __shared__ float  s_ta[OO];
    __shared__ int    s_lab[OO];
    __shared__ unsigned long long s_k[TC][256];
    if (tid < OO){
        const float* t = targets + ((size_t)b*OO + tid)*5;
        float x0=t[0],y0=t[1],x1=t[2],y1=t[3];
        s_tb[tid] = make_float4(x0,y0,x1,y1);
        s_ta[tid] = (x1-x0)*(y1-y0);
        s_lab[tid]= (int)t[4];
    }
    __syncthreads();

    float px0[NPL],py0[NPL],px1[NPL],py1[NPL],pa[NPL];
    #pragma unroll
    for (int j=0;j<NPL;j++){
        float4 pr = ((const float4*)priors)[p0 + j*256];
        float hw=pr.z*0.5f, hh=pr.w*0.5f;
        px0[j]=pr.x-hw; py0[j]=pr.y-hh; px1[j]=pr.x+hw; py1[j]=pr.y+hh;
        pa[j]=(px1[j]-px0[j])*(py1[j]-py0[j]);
    }
    float binter[NPL], bs[NPL]; int bi[NPL];
    #pragma unroll
    for (int j=0;j<NPL;j++){ binter[j]=-1.f; bs[j]=1.f; bi[j]=0; }

    for (int c=0; c<OO/TC; ++c){
        unsigned long long k8[TC];
        #pragma unroll
        for (int tt=0; tt<TC; ++tt){
            const int t = c*TC + tt;
            float4 tb = s_tb[t];
            float ta = s_ta[t];
            float cin=-1.f, csn=1.f; unsigned cp=0;
            #pragma unroll
            for (int j=0;j<NPL;j++){
                float ltx=fmaxf(tb.x,px0[j]), lty=fmaxf(tb.y,py0[j]);
                float rbx=fminf(tb.z,px1[j]), rby=fminf(tb.w,py1[j]);
                float w=fmaxf(rbx-ltx,0.f), h=fmaxf(rby-lty,0.f);
                float inter=w*h;
                float s = ta + pa[j];
                if (inter*bs[j] > binter[j]*s){ binter[j]=inter; bs[j]=s; bi[j]=t; }
                if (inter*csn > cin*s){ cin=inter; csn=s; cp=(unsigned)(p0 + j*256); }
            }
            float iou = cin / (csn - cin);           // reference f32 rounding
            k8[tt] = ((unsigned long long)__float_as_uint(iou)<<32)
                   | (unsigned long long)(0xFFFFFFFFu - cp);
        }
        __syncthreads();     // previous chunk's readers done
        #pragma unroll
        for (int tt=0; tt<TC; ++tt) s_k[tt][tid] = k8[tt];
        __syncthreads();
        const int r = tid >> 5, sub = tid & 31;
        unsigned long long m = s_k[r][sub];
        #pragma unroll
        for (int q=1;q<8;q++){
            unsigned long long o = s_k[r][sub + 32*q];
            if (o > m) m = o;
        }
        m = hmax32(m);                               // tie -> smaller p (~p field)
        if (sub == 0) atomicMax(&bp[b*OO + c*TC + r], m);
    }

    // tail: unforced conf/lse/vals + positive accumulation (forcing in k_selfix)
    float l_ls=0.f, l_cs=0.f; int l_np=0;
    #pragma unroll
    for (int j=0;j<NPL;j++){
        int p = p0 + j*256;
        float biou = binter[j] / (bs[j] - binter[j]);
        int c = (biou < TH) ? 0 : (s_lab[bi[j]] + 1);
        float2 cd = ((const float2*)conf)[(size_t)b*PP + p];
        float mx = fmaxf(cd.x, cd.y);
        float lse = mx + log1pf(expf(fminf(cd.x,cd.y)-mx));
        float lca = lse - ((c>=1)? cd.y : cd.x);
        bool pos = c>0;
        vals[(size_t)b*PP + p] = pos ? 0.f : lca;
        if (pos){
            float4 pr = ((const float4*)priors)[p];
            float4 tb = s_tb[bi[j]];
            float4 ld = ((const float4*)loc)[(size_t)b*PP + p];
            l_ls += locloss(tb.x,tb.y,tb.z,tb.w, pr, ld);
            l_cs += lca; l_np++;
        }
    }
    #pragma unroll
    for (int d=1; d<64; d<<=1){
        l_ls += __shfl_xor(l_ls,d);
        l_cs += __shfl_xor(l_cs,d);
        l_np += __shfl_xor(l_np,d);
    }
    if (lane==0){
        atomicAdd(&lsum_b[b], l_ls);
        atomicAdd(&csum_b[b], l_cs);
        atomicAdd(&npos_b[b], l_np);
    }
}

// Descending-bin radix scan over h[0..N-1] by one 64-lane wave (C bins/lane).
// Finds bin b* where cumulative-from-top first reaches kX; outputs b* and
// the remaining count within that bin.
__device__ __forceinline__ void scan_desc(const unsigned* h, int N, int C,
                                          unsigned kX, unsigned* s_b, unsigned* s_kN,
                                          int lane){
    int base = N - 1 - C*lane;
    unsigned csum = 0;
    for (int q=0;q<C;q++) csum += h[base-q];
    unsigned inc = csum;
    #pragma unroll
    for (int d=1; d<64; d<<=1){
        unsigned o = __shfl_up(inc, d);
        if (lane >= d) inc += o;
    }
    unsigned excl = inc - csum;
    if (excl < kX && kX <= inc){
        unsigned cum = excl;
        for (int q=0;q<C;q++){
            unsigned hv = h[base-q];
            cum += hv;
            if (cum >= kX){ *s_b = (unsigned)(base-q); *s_kN = kX - (cum - hv); break; }
        }
    }
}

// Phase A: forcing fixup (<=32 priors, last-writer-wins).
// Phase B: exact sum-of-top-k via 3-pass histogram radix (11+10+10 bits).
__global__ __launch_bounds__(1024) void k_selfix(
        const float* __restrict__ loc, const float* __restrict__ conf,
        const float* __restrict__ priors, const float* __restrict__ targets,
        const unsigned long long* __restrict__ bp,
        float* __restrict__ vals,
        float* __restrict__ lsum_b, float* __restrict__ csum_b, int* __restrict__ npos_b,
        float* __restrict__ sS){
    const int b = blockIdx.x;
    const int tid = threadIdx.x;
    __shared__ float4 s_tb[OO];
    __shared__ float  s_ta[OO];
    __shared__ int    s_lab[OO];
    __shared__ unsigned s_p[OO];
    __shared__ unsigned h[2048];
    __shared__ unsigned s_bd[3];   // digits A,B,C
    __shared__ unsigned s_kx[3];   // remaining counts after A,B,C
    __shared__ float s_sumf;
    __shared__ unsigned s_cntg;
    __shared__ int s_kint;
    if (tid < OO){
        const float* tt = targets + ((size_t)b*OO + tid)*5;
        s_tb[tid] = make_float4(tt[0],tt[1],tt[2],tt[3]);
        s_ta[tid] = (tt[2]-tt[0])*(tt[3]-tt[1]);
        s_lab[tid]= (int)tt[4];
        s_p[tid]  = 0xFFFFFFFFu - (unsigned)(bp[b*OO + tid] & 0xFFFFFFFFull);
    }
    h[tid] = 0; h[tid+1024] = 0;
    if (tid == 0){ s_sumf = 0.f; s_cntg = 0; }
    __syncthreads();
    if (tid < OO){
        unsigned p = s_p[tid];
        bool last = true;
        for (int t2=tid+1; t2<OO; t2++) if (s_p[t2]==p) last = false;
        if (last){
            float4 pr = ((const float4*)priors)[p];
            float hw=pr.z*0.5f, hh=pr.w*0.5f;
            float qx0=pr.x-hw, qy0=pr.y-hh, qx1=pr.x+hw, qy1=pr.y+hh;
            float qa=(qx1-qx0)*(qy1-qy0);
            float binter=-1.f, bss=1.f; int bi=0;
            for (int k2=0;k2<OO;k2++){
                float4 tb = s_tb[k2];
                float ltx=fmaxf(tb.x,qx0), lty=fmaxf(tb.y,qy0);
                float rbx=fminf(tb.z,qx1), rby=fminf(tb.w,qy1);
                float w=fmaxf(rbx-ltx,0.f), h2=fmaxf(rby-lty,0.f);
                float inter=w*h2; float s=s_ta[k2]+qa;
                if (inter*bss > binter*s){ binter=inter; bss=s; bi=k2; }
            }
            float biou = binter/(bss-binter);
            int  c0   = (biou < TH) ? 0 : (s_lab[bi] + 1);
            bool pos0 = c0 > 0;
            float2 cd = ((const float2*)conf)[(size_t)b*PP + p];
            float mx  = fmaxf(cd.x, cd.y);
            float lse = mx + log1pf(expf(fminf(cd.x,cd.y)-mx));
            float lca0 = lse - ((c0 >= 1) ? cd.y : cd.x);
            int   cn   = s_lab[tid] + 1;
            float lcan = lse - ((cn >= 1) ? cd.y : cd.x);
            float4 ld  = ((const float4*)loc)[(size_t)b*PP + p];
            float4 tbn = s_tb[tid];
            float lln = locloss(tbn.x,tbn.y,tbn.z,tbn.w, pr, ld);
            float ll0 = 0.f;
            if (pos0){
                float4 tb0 = s_tb[bi];
                ll0 = locloss(tb0.x,tb0.y,tb0.z,tb0.w, pr, ld);
            }
            atomicAdd(&lsum_b[b], lln - ll0);
            atomicAdd(&csum_b[b], lcan - (pos0 ? lca0 : 0.f));
            if (!pos0) atomicAdd(&npos_b[b], 1);
            vals[(size_t)b*PP + p] = 0.f;
        }
    }
    __syncthreads();
    if (tid == 0){
        int np = atomicAdd(&npos_b[b], 0);
        int kk = 3*np; if (kk > PP-1) kk = PP-1;
        s_kint = kk;
    }
    __syncthreads();
    const int k = s_kint;
    const unsigned* g = (const unsigned*)(vals + (size_t)b*PP);
    unsigned uv[25];
    #pragma unroll
    for (int i=0;i<25;i++) uv[i] = g[tid + (i<<10)];

    if (k > 0){
        // ---- pass A: bits [30:20], 2048 bins (h already zeroed) ----
        #pragma unroll
        for (int i=0;i<25;i++) atomicAdd(&h[uv[i]>>20], 1u);
        __syncthreads();
        if (tid < 64) scan_desc(h, 2048, 32, (unsigned)k, &s_bd[0], &s_kx[0], tid);
        __syncthreads();
        const unsigned bA = s_bd[0];
        const unsigned kB = s_kx[0];
        // ---- pass B: bits [19:10] among class A ----
        h[tid] = 0;
        __syncthreads();
        #pragma unroll
        for (int i=0;i<25;i++)
            if ((uv[i]>>20) == bA) atomicAdd(&h[(uv[i]>>10)&1023], 1u);
        __syncthreads();
        if (tid < 64) scan_desc(h, 1024, 16, kB, &s_bd[1], &s_kx[1], tid);
        __syncthreads();
        const unsigned pref21 = (bA<<10) | s_bd[1];
        const unsigned kC = s_kx[1];
        // ---- pass C: bits [9:0] among class AB ----
        h[tid] = 0;
        __syncthreads();
        #pragma unroll
        for (int i=0;i<25;i++)
            if ((uv[i]>>10) == pref21) atomicAdd(&h[uv[i]&1023], 1u);
        __syncthreads();
        if (tid < 64) scan_desc(h, 1024, 16, kC, &s_bd[2], &s_kx[2], tid);
        __syncthreads();
        const unsigned T = (pref21<<10) | s_bd[2];
        // ---- exact sum: values > T, plus (k - cnt_gt) copies of T ----
        unsigned cg = 0; float sg = 0.f;
        #pragma unroll
        for (int i=0;i<25;i++){
            unsigned u = uv[i];
            if (u > T){ cg++; sg += __uint_as_float(u); }
        }
        #pragma unroll
        for (int d=32; d; d>>=1){ cg += __shfl_down(cg,d); sg += __shfl_down(sg,d); }
        if ((tid & 63)==0){ if (cg) atomicAdd(&s_cntg, cg); atomicAdd(&s_sumf, sg); }
        __syncthreads();
        if (tid == 0)
            sS[b] = s_sumf + (float)(k - (int)s_cntg) * __uint_as_float(T);
    } else {
        if (tid == 0) sS[b] = 0.f;
    }
}

__global__ void k_fin(const float* __restrict__ lsum_b, const float* __restrict__ csum_b,
                      const int* __restrict__ npos_b, const float* __restrict__ sS,
                      float* __restrict__ out){
    int t = threadIdx.x;           // 64 lanes == BB
    float ls = lsum_b[t];
    float cs = csum_b[t] + sS[t];
    int   np = npos_b[t];
    #pragma unroll
    for (int d=32; d; d>>=1){
        ls += __shfl_down(ls,d);
        cs += __shfl_down(cs,d);
        np += __shfl_down(np,d);
    }
    if (t==0){
        float N = fmaxf((float)np, 1.f);
        out[0] = ls / N;
        out[1] = cs / N;
    }
}

extern "C" void kernel_launch(void* const* d_in, const int* in_sizes, int n_in,
                              void* d_out, int out_size, void* d_ws, size_t ws_size,
                              hipStream_t stream){
    const float* loc     = (const float*)d_in[0];
    const float* conf    = (const float*)d_in[1];
    const float* priors  = (const float*)d_in[2];
    const float* targets = (const float*)d_in[3];
    float* out = (float*)d_out;
    char* ws = (char*)d_ws;

    unsigned long long* bp = (unsigned long long*)ws;       // [0,16384)
    float* lsum_b = (float*)(ws + 16384);
    float* csum_b = (float*)(ws + 16640);
    int*   npos_b = (int*)  (ws + 16896);
    float* sS     = (float*)(ws + 17152);
    float* vals   = (float*)(ws + 17408);                   // 6.55 MB

    hipMemsetAsync(ws, 0, 17408, stream);
    k_main<<<dim3(GX, BB), 256, 0, stream>>>(loc, conf, priors, targets,
                                             bp, vals, lsum_b, csum_b, npos_b);
    k_selfix<<<BB, 1024, 0, stream>>>(loc, conf, priors, targets, bp, vals,
                                      lsum_b, csum_b, npos_b, sS);
    k_fin<<<1, 64, 0, stream>>>(lsum_b, csum_b, npos_b, sS, out);
}